// Round 6
// baseline (114.742 us; speedup 1.0000x reference)
//
#include <hip/hip_runtime.h>

typedef float f4 __attribute__((ext_vector_type(4)));
typedef short s4 __attribute__((ext_vector_type(4)));
typedef short s8 __attribute__((ext_vector_type(8)));
typedef unsigned int u32;

#define SCALE 0.17677669529663687f

static __device__ __forceinline__ short bf16c(float f) {
  u32 u = __builtin_bit_cast(u32, f);
  u32 r = u + 0x7fffu + ((u >> 16) & 1u);
  return (short)(r >> 16);
}

static __device__ __forceinline__ f4 mfma32(s8 a, s8 b, f4 c) {
  return __builtin_amdgcn_mfma_f32_16x16x32_bf16(a, b, c, 0, 0, 0);
}
// Zero-padded effective K=16 (slot-symmetric, layout-safe).
static __device__ __forceinline__ f4 bmm16(s4 a, s4 b, f4 c) {
  s8 A = {a[0], a[1], a[2], a[3], (short)0, (short)0, (short)0, (short)0};
  s8 B = {b[0], b[1], b[2], b[3], (short)0, (short)0, (short)0, (short)0};
  return __builtin_amdgcn_mfma_f32_16x16x32_bf16(A, B, c, 0, 0, 0);
}

#define XSTRIDE 280  // bytes per x^T row in LDS: 128 bf16 = 256B + 24B pad

// ---------------------------------------------------------------------------
// Kernel A: fused KV 1x1-conv (MFMA) + exp + ctx accumulation.
// Templated on NCH (n-chunks per batch). Grid (NCH, 16 b); 4 waves = 4 heads.
// NCH=64 -> 1024 blocks = 4 blocks/CU (LDS-limited) = 16 waves/CU.
// ---------------------------------------------------------------------------
template <int NCH>
__global__ __launch_bounds__(256) void ctx_kernel(
    const float* __restrict__ x, const float* __restrict__ wqkv,
    float* __restrict__ cp, float* __restrict__ zp)
{
  constexpr int NT = 16384 / NCH / 64;  // 64n tiles per block
  const int chunk = blockIdx.x, b = blockIdx.y;
  const int tid = threadIdx.x, lane = tid & 63, h = tid >> 6;
  __shared__ __align__(16) char lds[2 * 64 * XSTRIDE];  // 35840 B

  s8 wf[4][4];
  {
    const int colr = lane & 15, g = lane >> 4;
#pragma unroll
    for (int s = 0; s < 4; ++s) {
      const int grow = (s < 2 ? 128 : 256) + h * 32 + (s & 1) * 16 + colr;
#pragma unroll
      for (int kc = 0; kc < 4; ++kc) {
        const float* src = wqkv + grow * 128 + kc * 32 + g * 8;
        const f4 a = *(const f4*)src;
        const f4 c2 = *(const f4*)(src + 4);
        s8 t = {bf16c(a[0]), bf16c(a[1]), bf16c(a[2]), bf16c(a[3]),
                bf16c(c2[0]), bf16c(c2[1]), bf16c(c2[2]), bf16c(c2[3])};
        wf[s][kc] = t;
      }
    }
  }

  f4 ctxacc[2][2];
#pragma unroll
  for (int a = 0; a < 2; ++a)
#pragma unroll
    for (int e2 = 0; e2 < 2; ++e2) ctxacc[a][e2] = (f4){0.f, 0.f, 0.f, 0.f};
  float zloc[2] = {0.f, 0.f};

  const float* xb = x + (size_t)b * 128 * 16384 + chunk * (NT * 64);
  const int nq = tid & 15, ch = tid >> 4;
  f4 v[2][4];

  auto aload = [&](int tl) {
#pragma unroll
    for (int q = 0; q < 2; ++q) {
      const int c0 = ch * 4 + q * 64;
#pragma unroll
      for (int i = 0; i < 4; ++i)
        v[q][i] = *(const f4*)(xb + (size_t)(c0 + i) * 16384 + tl * 64 + nq * 4);
    }
  };
  auto awrite = [&](int buf) {
#pragma unroll
    for (int q = 0; q < 2; ++q) {
      const int c0 = ch * 4 + q * 64;
#pragma unroll
      for (int j = 0; j < 4; ++j) {
        s4 t = {bf16c(v[q][0][j]), bf16c(v[q][1][j]), bf16c(v[q][2][j]),
                bf16c(v[q][3][j])};
        *(s4*)(lds + buf * (64 * XSTRIDE) + (nq * 4 + j) * XSTRIDE + c0 * 2) = t;
      }
    }
  };
  auto compute = [&](int buf) {
#pragma unroll
    for (int nt = 0; nt < 4; ++nt) {
      const char* rp =
          lds + buf * (64 * XSTRIDE) + (nt * 16 + (lane & 15)) * XSTRIDE +
          (lane >> 4) * 16;
      s8 af[4];
#pragma unroll
      for (int kc = 0; kc < 4; ++kc) {
        const s4 lo = *(const s4*)(rp + kc * 64);
        const s4 hi = *(const s4*)(rp + kc * 64 + 8);
        af[kc] = __builtin_shufflevector(lo, hi, 0, 1, 2, 3, 4, 5, 6, 7);
      }
      f4 acc[4];
#pragma unroll
      for (int s = 0; s < 4; ++s) acc[s] = (f4){0.f, 0.f, 0.f, 0.f};
#pragma unroll
      for (int kc = 0; kc < 4; ++kc)
#pragma unroll
        for (int s = 0; s < 4; ++s)
          acc[s] = mfma32(af[kc], wf[s][kc], acc[s]);
      f4 e0, e1;
#pragma unroll
      for (int r = 0; r < 4; ++r) {
        e0[r] = __expf(acc[0][r]);
        e1[r] = __expf(acc[1][r]);
      }
      zloc[0] += e0[0] + e0[1] + e0[2] + e0[3];
      zloc[1] += e1[0] + e1[1] + e1[2] + e1[3];
      const s4 ea0 = {bf16c(e0[0]), bf16c(e0[1]), bf16c(e0[2]), bf16c(e0[3])};
      const s4 ea1 = {bf16c(e1[0]), bf16c(e1[1]), bf16c(e1[2]), bf16c(e1[3])};
      const s4 vb0 = {bf16c(acc[2][0]), bf16c(acc[2][1]), bf16c(acc[2][2]),
                      bf16c(acc[2][3])};
      const s4 vb1 = {bf16c(acc[3][0]), bf16c(acc[3][1]), bf16c(acc[3][2]),
                      bf16c(acc[3][3])};
      ctxacc[0][0] = bmm16(ea0, vb0, ctxacc[0][0]);
      ctxacc[0][1] = bmm16(ea0, vb1, ctxacc[0][1]);
      ctxacc[1][0] = bmm16(ea1, vb0, ctxacc[1][0]);
      ctxacc[1][1] = bmm16(ea1, vb1, ctxacc[1][1]);
    }
  };

  aload(0);
  awrite(0);
  __syncthreads();
  for (int tl = 0; tl < NT; ++tl) {
    if (tl < NT - 1) aload(tl + 1);
    compute(tl & 1);
    if (tl < NT - 1) awrite((tl + 1) & 1);
    __syncthreads();
  }

  {
    const size_t base = (size_t)((b * 4 + h) * NCH + chunk) * 1024;
    const int g4 = (lane >> 4) * 4, cc = lane & 15;
#pragma unroll
    for (int a = 0; a < 2; ++a)
#pragma unroll
      for (int e2 = 0; e2 < 2; ++e2)
#pragma unroll
        for (int r = 0; r < 4; ++r)
          cp[base + (size_t)(a * 16 + g4 + r) * 32 + e2 * 16 + cc] =
              ctxacc[a][e2][r];
  }
#pragma unroll
  for (int s = 0; s < 2; ++s) {
    float z = zloc[s];
    z += __shfl_xor(z, 16);
    z += __shfl_xor(z, 32);
    if (lane < 16)
      zp[((b * 4 + h) * NCH + chunk) * 32 + s * 16 + lane] = z;
  }
}

// ---------------------------------------------------------------------------
// Reduce partials over chunks (NCH=64 path). Grid 256: bh = bid>>2, quarter.
// ---------------------------------------------------------------------------
__global__ __launch_bounds__(256) void reduce_ctx(
    const float* __restrict__ cp, const float* __restrict__ zp,
    float* __restrict__ ctx_red, float* __restrict__ z_red)
{
  const int bh = blockIdx.x >> 2, part = blockIdx.x & 3;
  const int t = threadIdx.x;
  const int idx = part * 256 + t;
  float s = 0.f;
  const float* src = cp + (size_t)bh * 64 * 1024 + idx;
#pragma unroll 8
  for (int ch = 0; ch < 64; ++ch) s += src[ch * 1024];
  ctx_red[(size_t)bh * 1024 + idx] = s;
  if (part == 0 && t < 32) {
    float z = 0.f;
#pragma unroll 8
    for (int ch = 0; ch < 64; ++ch) z += zp[((size_t)bh * 64 + ch) * 32 + t];
    z_red[bh * 32 + t] = z;
  }
}

// ---------------------------------------------------------------------------
// Kernel B (fast path): reads pre-reduced ctx. Grid (8 rg, 16 b).
// ---------------------------------------------------------------------------
__global__ __launch_bounds__(256, 2) void makeP_fast(
    const float* __restrict__ ctx_red, const float* __restrict__ z_red,
    const float* __restrict__ wout, const float* __restrict__ wqkv,
    unsigned short* __restrict__ Phi)
{
  const int rg = blockIdx.x, b = blockIdx.y, t = threadIdx.x;
  __shared__ float ctxn[4096];
  __shared__ float zs[128];
  __shared__ float Ms[16][129];

  if (t < 128) zs[t] = z_red[(b * 4 + (t >> 5)) * 32 + (t & 31)];
  __syncthreads();
  {
    const int i0 = t * 16, hh = i0 >> 10;
    const float zinv = 1.f / zs[i0 >> 5];
    const float* src = ctx_red + (size_t)(b * 4 + hh) * 1024 + (i0 & 1023);
    *(f4*)(ctxn + i0)      = *(const f4*)(src)      * zinv;
    *(f4*)(ctxn + i0 + 4)  = *(const f4*)(src + 4)  * zinv;
    *(f4*)(ctxn + i0 + 8)  = *(const f4*)(src + 8)  * zinv;
    *(f4*)(ctxn + i0 + 12) = *(const f4*)(src + 12) * zinv;
  }
  __syncthreads();
  {
    const int o = t >> 4, hd0 = (t & 15) * 8;
    const int hh = hd0 >> 5;
    f4 wseg[8];
    const float* wp = wout + (size_t)(rg * 16 + o) * 128 + hh * 32;
#pragma unroll
    for (int i = 0; i < 8; ++i) wseg[i] = *(const f4*)(wp + i * 4);
#pragma unroll
    for (int j = 0; j < 8; ++j) {
      const float* cn = ctxn + (hd0 + j) * 32;
      f4 acc = {0.f, 0.f, 0.f, 0.f};
#pragma unroll
      for (int i = 0; i < 8; ++i) acc += wseg[i] * *(const f4*)(cn + i * 4);
      Ms[o][hd0 + j] = acc[0] + acc[1] + acc[2] + acc[3];
    }
  }
  __syncthreads();
  {
    const int o = t >> 4, c0 = (t & 15) * 8;
    f4 a0 = {0.f,0.f,0.f,0.f}, a1 = a0;
#pragma unroll 8
    for (int hd = 0; hd < 128; ++hd) {
      const float m = Ms[o][hd];
      const float* wp = wqkv + (size_t)hd * 128 + c0;
      a0 += m * *(const f4*)(wp);
      a1 += m * *(const f4*)(wp + 4);
    }
    a0 *= SCALE;
    a1 *= SCALE;
    s8 out = {bf16c(a0[0]), bf16c(a0[1]), bf16c(a0[2]), bf16c(a0[3]),
              bf16c(a1[0]), bf16c(a1[1]), bf16c(a1[2]), bf16c(a1[3])};
    *(s8*)(Phi + ((size_t)b * 128 + rg * 16 + o) * 128 + c0) = out;
  }
}

// ---------------------------------------------------------------------------
// Kernel B (fallback, NCH=16): round-5 proven version with in-kernel reduce.
// ---------------------------------------------------------------------------
__global__ __launch_bounds__(256, 2) void makeP_full(
    const float* __restrict__ cp, const float* __restrict__ zp,
    const float* __restrict__ wout, const float* __restrict__ wqkv,
    unsigned short* __restrict__ Phi)
{
  const int rg = blockIdx.x, b = blockIdx.y, t = threadIdx.x;
  __shared__ float ctxn[4096];
  __shared__ float zs[128];
  __shared__ float Ms[16][129];

  if (t < 128) {
    float s = 0.f;
#pragma unroll
    for (int ch = 0; ch < 16; ++ch)
      s += zp[((size_t)(b * 4 + (t >> 5)) * 16 + ch) * 32 + (t & 31)];
    zs[t] = s;
  }
  __syncthreads();
  {
    const int i0 = t * 16;
    const int hh = i0 >> 10;
    f4 s0 = {0.f,0.f,0.f,0.f}, s1 = s0, s2 = s0, s3 = s0;
    const float* src = cp + ((size_t)(b * 4 + hh) * 16) * 1024 + (i0 & 1023);
#pragma unroll
    for (int ch = 0; ch < 16; ++ch) {
      const float* p = src + ch * 1024;
      s0 += *(const f4*)(p);
      s1 += *(const f4*)(p + 4);
      s2 += *(const f4*)(p + 8);
      s3 += *(const f4*)(p + 12);
    }
    const float zinv = 1.f / zs[i0 >> 5];
    *(f4*)(ctxn + i0)      = s0 * zinv;
    *(f4*)(ctxn + i0 + 4)  = s1 * zinv;
    *(f4*)(ctxn + i0 + 8)  = s2 * zinv;
    *(f4*)(ctxn + i0 + 12) = s3 * zinv;
  }
  __syncthreads();
  {
    const int o = t >> 4, hd0 = (t & 15) * 8;
    const int hh = hd0 >> 5;
    f4 wseg[8];
    const float* wp = wout + (size_t)(rg * 16 + o) * 128 + hh * 32;
#pragma unroll
    for (int i = 0; i < 8; ++i) wseg[i] = *(const f4*)(wp + i * 4);
#pragma unroll
    for (int j = 0; j < 8; ++j) {
      const float* cn = ctxn + (hd0 + j) * 32;
      f4 acc = {0.f, 0.f, 0.f, 0.f};
#pragma unroll
      for (int i = 0; i < 8; ++i) acc += wseg[i] * *(const f4*)(cn + i * 4);
      Ms[o][hd0 + j] = acc[0] + acc[1] + acc[2] + acc[3];
    }
  }
  __syncthreads();
  {
    const int o = t >> 4, c0 = (t & 15) * 8;
    f4 a0 = {0.f,0.f,0.f,0.f}, a1 = a0;
#pragma unroll 8
    for (int hd = 0; hd < 128; ++hd) {
      const float m = Ms[o][hd];
      const float* wp = wqkv + (size_t)hd * 128 + c0;
      a0 += m * *(const f4*)(wp);
      a1 += m * *(const f4*)(wp + 4);
    }
    a0 *= SCALE;
    a1 *= SCALE;
    s8 out = {bf16c(a0[0]), bf16c(a0[1]), bf16c(a0[2]), bf16c(a0[3]),
              bf16c(a1[0]), bf16c(a1[1]), bf16c(a1[2]), bf16c(a1[3])};
    *(s8*)(Phi + ((size_t)b * 128 + rg * 16 + o) * 128 + c0) = out;
  }
}

// ---------------------------------------------------------------------------
// Kernel C: y[b] = P_b · x[b] + bias as D = x^T · P^T.  (unchanged)
// ---------------------------------------------------------------------------
__global__ __launch_bounds__(256) void out_gemm(
    const float* __restrict__ x, const unsigned short* __restrict__ Phi,
    const float* __restrict__ bias, float* __restrict__ y)
{
  const int nb = blockIdx.x, b = blockIdx.y;
  const int tid = threadIdx.x, lane = tid & 63, w = tid >> 6;
  __shared__ __align__(16) char lds[128 * XSTRIDE];  // 35840 B

  s8 pf[2][4];
#pragma unroll
  for (int ot2 = 0; ot2 < 2; ++ot2) {
    const int orow = (w * 2 + ot2) * 16 + (lane & 15);
#pragma unroll
    for (int kc = 0; kc < 4; ++kc)
      pf[ot2][kc] = *(const s8*)(Phi + ((size_t)b * 128 + orow) * 128 +
                                 kc * 32 + (lane >> 4) * 8);
  }

  const float* xb = x + (size_t)b * 128 * 16384 + (size_t)nb * 128;
  {
    const int nq = tid & 31, ch = tid >> 5;
#pragma unroll
    for (int q = 0; q < 4; ++q) {
      const int c0 = ch * 4 + q * 32;
      f4 v[4];
#pragma unroll
      for (int i = 0; i < 4; ++i)
        v[i] = *(const f4*)(xb + (size_t)(c0 + i) * 16384 + nq * 4);
#pragma unroll
      for (int j = 0; j < 4; ++j) {
        s4 t = {bf16c(v[0][j]), bf16c(v[1][j]), bf16c(v[2][j]), bf16c(v[3][j])};
        *(s4*)(lds + (nq * 4 + j) * XSTRIDE + c0 * 2) = t;
      }
    }
  }
  __syncthreads();

  f4 acc[8][2];
#pragma unroll
  for (int nt = 0; nt < 8; ++nt)
#pragma unroll
    for (int ot2 = 0; ot2 < 2; ++ot2) acc[nt][ot2] = (f4){0.f, 0.f, 0.f, 0.f};

#pragma unroll
  for (int nt = 0; nt < 8; ++nt) {
    const char* rp = lds + (nt * 16 + (lane & 15)) * XSTRIDE + (lane >> 4) * 16;
    s8 af[4];
#pragma unroll
    for (int kc = 0; kc < 4; ++kc) {
      const s4 lo = *(const s4*)(rp + kc * 64);
      const s4 hi = *(const s4*)(rp + kc * 64 + 8);
      af[kc] = __builtin_shufflevector(lo, hi, 0, 1, 2, 3, 4, 5, 6, 7);
    }
#pragma unroll
    for (int kc = 0; kc < 4; ++kc)
#pragma unroll
      for (int ot2 = 0; ot2 < 2; ++ot2)
        acc[nt][ot2] = mfma32(af[kc], pf[ot2][kc], acc[nt][ot2]);
  }

  const int g4 = (lane >> 4) * 4;
#pragma unroll
  for (int ot2 = 0; ot2 < 2; ++ot2) {
    const int o = (w * 2 + ot2) * 16 + (lane & 15);
    const float bv = bias[o];
    float* yo = y + ((size_t)b * 128 + o) * 16384 + (size_t)nb * 128;
#pragma unroll
    for (int nt = 0; nt < 8; ++nt) {
      f4 o4 = acc[nt][ot2];
      o4[0] += bv; o4[1] += bv; o4[2] += bv; o4[3] += bv;
      *(f4*)(yo + nt * 16 + g4) = o4;
    }
  }
}

extern "C" void kernel_launch(void* const* d_in, const int* in_sizes, int n_in,
                              void* d_out, int out_size, void* d_ws, size_t ws_size,
                              hipStream_t stream) {
  const float* x = (const float*)d_in[0];
  const float* wqkv = (const float*)d_in[1];
  const float* wout = (const float*)d_in[2];
  const float* bias = (const float*)d_in[3];
  float* ws = (float*)d_ws;
  float* y = (float*)d_out;

  // NCH=64 layout: cp [16*4*64*1024] | zp [16*4*64*32] | ctx_red [16*4*1024]
  //                | z_red [16*4*32] | Phi bf16 [16*128*128]
  const size_t CPN64 = (size_t)16 * 4 * 64 * 1024;   // 4,194,304 floats
  const size_t ZPN64 = (size_t)16 * 4 * 64 * 32;     //   131,072 floats
  const size_t need64 = (CPN64 + ZPN64 + 65536 + 2048) * 4 + 262144 * 2;

  if (ws_size >= need64) {
    float* cp = ws;
    float* zp = cp + CPN64;
    float* ctx_red = zp + ZPN64;
    float* z_red = ctx_red + 65536;
    unsigned short* Phi = (unsigned short*)(z_red + 2048);
    ctx_kernel<64><<<dim3(64, 16), 256, 0, stream>>>(x, wqkv, cp, zp);
    reduce_ctx<<<dim3(256), 256, 0, stream>>>(cp, zp, ctx_red, z_red);
    makeP_fast<<<dim3(8, 16), 256, 0, stream>>>(ctx_red, z_red, wout, wqkv, Phi);
    out_gemm<<<dim3(128, 16), 256, 0, stream>>>(x, Phi, bias, y);
  } else {
    // Round-5 proven fallback (4.85 MB)
    float* cp = ws;                                   // [16][4][16][1024]
    float* zp = cp + 1048576;                         // [16][4][16][32]
    unsigned short* Phi = (unsigned short*)(cp + 1081344);
    ctx_kernel<16><<<dim3(16, 16), 256, 0, stream>>>(x, wqkv, cp, zp);
    makeP_full<<<dim3(8, 16), 256, 0, stream>>>(cp, zp, wout, wqkv, Phi);
    out_gemm<<<dim3(128, 16), 256, 0, stream>>>(x, Phi, bias, y);
  }
}